// Round 2
// baseline (3658.950 us; speedup 1.0000x reference)
//
#include <hip/hip_runtime.h>

// GCN 2-layer: N=100000 nodes (dim 128 -> 64 -> 4), E=3.2M edges.
// Pipeline: deg -> dinv -> norm -> gemm1 -> scatter1 -> post1(leakyrelu)
//           -> gemm2 -> scatter2 -> post2(softmax)

__global__ void k_init_deg(float* __restrict__ deg, int n) {
    int i = blockIdx.x * blockDim.x + threadIdx.x;
    if (i < n) deg[i] = 1.0f;  // self-loop weight
}

__global__ void k_deg(const int* __restrict__ dst, const float* __restrict__ w,
                      float* __restrict__ deg, int E) {
    int e = blockIdx.x * blockDim.x + threadIdx.x;
    if (e < E) unsafeAtomicAdd(&deg[dst[e]], w[e]);
}

__global__ void k_dinv(float* __restrict__ deg, int n) {
    int i = blockIdx.x * blockDim.x + threadIdx.x;
    if (i < n) {
        float d = deg[i];
        deg[i] = d > 0.f ? rsqrtf(d) : 0.f;
    }
}

__global__ void k_norm(const int* __restrict__ src, const int* __restrict__ dst,
                       const float* __restrict__ w, const float* __restrict__ dinv,
                       float* __restrict__ norm, int E) {
    int e = blockIdx.x * blockDim.x + threadIdx.x;
    if (e < E) norm[e] = dinv[src[e]] * w[e] * dinv[dst[e]];
}

// h1[N][64] = x[N][128] @ W1[128][64].
// Block = 256 = 4 waves. Each wave: 32 rows, lane = output column.
// W chunk (32 k-values for this lane's column) held in registers; x rows read
// via wave-uniform addresses (scalar-load candidates). No LDS.
__global__ void __launch_bounds__(256) k_gemm1(const float* __restrict__ x,
                                               const float* __restrict__ W1,
                                               float* __restrict__ h1, int n) {
    int lane = threadIdx.x & 63;
    int wave = __builtin_amdgcn_readfirstlane(threadIdx.x >> 6);
    int r0 = (blockIdx.x * 4 + wave) * 32;
    if (r0 >= n) return;  // n % 32 == 0, so active waves always do 32 full rows

    float acc[32];
#pragma unroll
    for (int r = 0; r < 32; ++r) acc[r] = 0.f;

#pragma unroll 1
    for (int kc = 0; kc < 4; ++kc) {
        float wreg[32];
#pragma unroll
        for (int kk = 0; kk < 32; ++kk)
            wreg[kk] = W1[(kc * 32 + kk) * 64 + lane];
#pragma unroll
        for (int r = 0; r < 32; ++r) {
            const float4* xr = reinterpret_cast<const float4*>(
                x + (size_t)(r0 + r) * 128 + kc * 32);
#pragma unroll
            for (int q = 0; q < 8; ++q) {
                float4 xv = xr[q];
                acc[r] = fmaf(xv.x, wreg[q * 4 + 0], acc[r]);
                acc[r] = fmaf(xv.y, wreg[q * 4 + 1], acc[r]);
                acc[r] = fmaf(xv.z, wreg[q * 4 + 2], acc[r]);
                acc[r] = fmaf(xv.w, wreg[q * 4 + 3], acc[r]);
            }
        }
    }
#pragma unroll
    for (int r = 0; r < 32; ++r)
        h1[(size_t)(r0 + r) * 64 + lane] = acc[r];
}

// agg1[dst] += norm * h1[src], 64 dims. 16 threads per edge, float4 each.
__global__ void k_scatter1(const int* __restrict__ src, const int* __restrict__ dst,
                           const float* __restrict__ norm, const float* __restrict__ h1,
                           float* __restrict__ agg1, int E) {
    int t = blockIdx.x * blockDim.x + threadIdx.x;
    int e = t >> 4;
    int d4 = t & 15;
    if (e >= E) return;
    float nrm = norm[e];
    int s = src[e], d = dst[e];
    float4 hv = *reinterpret_cast<const float4*>(h1 + (size_t)s * 64 + d4 * 4);
    float* out = agg1 + (size_t)d * 64 + d4 * 4;
    unsafeAtomicAdd(out + 0, nrm * hv.x);
    unsafeAtomicAdd(out + 1, nrm * hv.y);
    unsafeAtomicAdd(out + 2, nrm * hv.z);
    unsafeAtomicAdd(out + 3, nrm * hv.w);
}

// y = leaky_relu(agg1 + dinv^2 * h1 + b1), in place into agg1.
__global__ void k_post1(const float* __restrict__ h1, const float* __restrict__ dinv,
                        const float* __restrict__ b1, float* __restrict__ agg1, int n) {
    int t = blockIdx.x * blockDim.x + threadIdx.x;  // n*16 threads
    if (t >= n * 16) return;
    int i = t >> 4, d4 = t & 15;
    float di = dinv[i];
    float sl = di * di;
    float4 a = reinterpret_cast<float4*>(agg1)[t];
    float4 h = reinterpret_cast<const float4*>(h1)[t];
    float4 b = reinterpret_cast<const float4*>(b1)[d4];
    float4 v;
    v.x = a.x + sl * h.x + b.x;
    v.y = a.y + sl * h.y + b.y;
    v.z = a.z + sl * h.z + b.z;
    v.w = a.w + sl * h.w + b.w;
    v.x = v.x > 0.f ? v.x : 0.01f * v.x;
    v.y = v.y > 0.f ? v.y : 0.01f * v.y;
    v.z = v.z > 0.f ? v.z : 0.01f * v.z;
    v.w = v.w > 0.f ? v.w : 0.01f * v.w;
    reinterpret_cast<float4*>(agg1)[t] = v;
}

// h2[N][4] = y[N][64] @ W2[64][4]. Thread per row; W2 staged in LDS.
__global__ void __launch_bounds__(256) k_gemm2(const float* __restrict__ y,
                                               const float* __restrict__ W2,
                                               float* __restrict__ h2, int n) {
    __shared__ float4 w2s[64];
    if (threadIdx.x < 64)
        w2s[threadIdx.x] = reinterpret_cast<const float4*>(W2)[threadIdx.x];
    __syncthreads();
    int i = blockIdx.x * blockDim.x + threadIdx.x;
    if (i >= n) return;
    const float4* yr = reinterpret_cast<const float4*>(y + (size_t)i * 64);
    float ax = 0.f, ay = 0.f, az = 0.f, aw = 0.f;
#pragma unroll
    for (int q = 0; q < 16; ++q) {
        float4 yv = yr[q];
#pragma unroll
        for (int j = 0; j < 4; ++j) {
            float yk = (j == 0) ? yv.x : (j == 1) ? yv.y : (j == 2) ? yv.z : yv.w;
            float4 wv = w2s[q * 4 + j];
            ax = fmaf(yk, wv.x, ax);
            ay = fmaf(yk, wv.y, ay);
            az = fmaf(yk, wv.z, az);
            aw = fmaf(yk, wv.w, aw);
        }
    }
    float4 acc = {ax, ay, az, aw};
    reinterpret_cast<float4*>(h2)[i] = acc;
}

// agg2[dst] += norm * h2[src], 4 dims. Thread per edge.
__global__ void k_scatter2(const int* __restrict__ src, const int* __restrict__ dst,
                           const float* __restrict__ norm, const float* __restrict__ h2,
                           float* __restrict__ agg2, int E) {
    int e = blockIdx.x * blockDim.x + threadIdx.x;
    if (e >= E) return;
    float nrm = norm[e];
    float4 hv = reinterpret_cast<const float4*>(h2)[src[e]];
    float* out = agg2 + (size_t)dst[e] * 4;
    unsafeAtomicAdd(out + 0, nrm * hv.x);
    unsafeAtomicAdd(out + 1, nrm * hv.y);
    unsafeAtomicAdd(out + 2, nrm * hv.z);
    unsafeAtomicAdd(out + 3, nrm * hv.w);
}

// out = softmax(agg2 + dinv^2 * h2 + b2) per row of 4.
__global__ void k_post2(const float* __restrict__ h2, const float* __restrict__ dinv,
                        const float* __restrict__ b2, const float* __restrict__ agg2,
                        float* __restrict__ out, int n) {
    int i = blockIdx.x * blockDim.x + threadIdx.x;
    if (i >= n) return;
    float di = dinv[i];
    float sl = di * di;
    float4 a = reinterpret_cast<const float4*>(agg2)[i];
    float4 h = reinterpret_cast<const float4*>(h2)[i];
    float4 b = *reinterpret_cast<const float4*>(b2);
    float vx = a.x + sl * h.x + b.x;
    float vy = a.y + sl * h.y + b.y;
    float vz = a.z + sl * h.z + b.z;
    float vw = a.w + sl * h.w + b.w;
    float m = fmaxf(fmaxf(vx, vy), fmaxf(vz, vw));
    float ex = expf(vx - m), ey = expf(vy - m), ez = expf(vz - m), ew = expf(vw - m);
    float inv = 1.0f / (ex + ey + ez + ew);
    float4 o = {ex * inv, ey * inv, ez * inv, ew * inv};
    reinterpret_cast<float4*>(out)[i] = o;
}

extern "C" void kernel_launch(void* const* d_in, const int* in_sizes, int n_in,
                              void* d_out, int out_size, void* d_ws, size_t ws_size,
                              hipStream_t stream) {
    const float* x  = (const float*)d_in[0];
    const int*   ei = (const int*)d_in[1];
    const float* w  = (const float*)d_in[2];
    const float* W1 = (const float*)d_in[3];
    const float* b1 = (const float*)d_in[4];
    const float* W2 = (const float*)d_in[5];
    const float* b2 = (const float*)d_in[6];
    int n = in_sizes[0] / 128;
    int E = in_sizes[2];
    const int* src = ei;
    const int* dst = ei + E;

    float* ws   = (float*)d_ws;
    float* dinv = ws;                       // n
    float* norm = dinv + n;                 // E
    float* h1   = norm + E;                 // n*64
    float* agg1 = h1 + (size_t)n * 64;      // n*64
    float* h2   = agg1 + (size_t)n * 64;    // n*4
    float* agg2 = h2 + (size_t)n * 4;       // n*4

    hipMemsetAsync(agg1, 0, (size_t)n * 64 * sizeof(float), stream);
    hipMemsetAsync(agg2, 0, (size_t)n * 4 * sizeof(float), stream);

    k_init_deg<<<(n + 255) / 256, 256, 0, stream>>>(dinv, n);
    k_deg<<<(E + 255) / 256, 256, 0, stream>>>(dst, w, dinv, E);
    k_dinv<<<(n + 255) / 256, 256, 0, stream>>>(dinv, n);
    k_norm<<<(E + 255) / 256, 256, 0, stream>>>(src, dst, w, dinv, norm, E);

    k_gemm1<<<(n + 127) / 128, 256, 0, stream>>>(x, W1, h1, n);

    long long s1t = (long long)E * 16;
    int s1grid = (int)((s1t + 255) / 256);
    k_scatter1<<<s1grid, 256, 0, stream>>>(src, dst, norm, h1, agg1, E);
    k_post1<<<(n * 16 + 255) / 256, 256, 0, stream>>>(h1, dinv, b1, agg1, n);

    k_gemm2<<<(n + 255) / 256, 256, 0, stream>>>(agg1, W2, h2, n);
    k_scatter2<<<(E + 255) / 256, 256, 0, stream>>>(src, dst, norm, h2, agg2, E);
    k_post2<<<(n + 255) / 256, 256, 0, stream>>>(h2, dinv, b2, agg2, (float*)d_out, n);
}

// Round 5
// 1281.884 us; speedup vs baseline: 2.8544x; 2.8544x over previous
//
#include <hip/hip_runtime.h>

// GCN 2-layer, atomic-free aggregation via per-call CSR build.
// Pipeline: hist -> scan(3) -> fill -> deg_csr(dinv) -> gemm1 ->
//           gather1(+self+bias+leakyrelu) -> gemm2 -> gather2(+self+bias+softmax)

#define SCAN_BLK 256

__global__ void k_hist(const int* __restrict__ dst, int* __restrict__ cnt, int E) {
    int e = blockIdx.x * blockDim.x + threadIdx.x;
    if (e < E) atomicAdd(&cnt[dst[e]], 1);
}

// exclusive scan, 3-kernel (block scan + block-sums scan + add-back)
__global__ void k_scan1(const int* __restrict__ cnt, int* __restrict__ pre,
                        int* __restrict__ bsum, int n) {
    __shared__ int s[SCAN_BLK];
    int i = blockIdx.x * SCAN_BLK + threadIdx.x;
    int v = (i < n) ? cnt[i] : 0;
    s[threadIdx.x] = v;
    __syncthreads();
#pragma unroll
    for (int off = 1; off < SCAN_BLK; off <<= 1) {
        int t = (threadIdx.x >= off) ? s[threadIdx.x - off] : 0;
        __syncthreads();
        s[threadIdx.x] += t;
        __syncthreads();
    }
    if (i < n) pre[i] = s[threadIdx.x] - v;  // exclusive
    if (threadIdx.x == SCAN_BLK - 1) bsum[blockIdx.x] = s[threadIdx.x];
}

__global__ void k_scan2(int* __restrict__ bsum, int nb) {  // nb <= 512, one block of 512
    __shared__ int s[512];
    int v = (threadIdx.x < nb) ? bsum[threadIdx.x] : 0;
    s[threadIdx.x] = v;
    __syncthreads();
#pragma unroll
    for (int off = 1; off < 512; off <<= 1) {
        int t = (threadIdx.x >= off) ? s[threadIdx.x - off] : 0;
        __syncthreads();
        s[threadIdx.x] += t;
        __syncthreads();
    }
    if (threadIdx.x < nb) bsum[threadIdx.x] = s[threadIdx.x] - v;
}

__global__ void k_scan3(int* __restrict__ pre, const int* __restrict__ bsum, int n) {
    int i = blockIdx.x * SCAN_BLK + threadIdx.x;
    if (i < n) pre[i] += bsum[blockIdx.x];
}

__global__ void k_fill(const int* __restrict__ dst, const int* __restrict__ row_s,
                       int* __restrict__ cursor, int* __restrict__ eidx, int E) {
    int e = blockIdx.x * blockDim.x + threadIdx.x;
    if (e < E) {
        int d = dst[e];
        int p = atomicAdd(&cursor[d], 1);
        eidx[row_s[d] + p] = e;
    }
}

// dinv[i] = rsqrt(1 + sum_{incoming} w)  (self-loop weight 1; deg >= 1 always)
__global__ void k_deg_csr(const int* __restrict__ eidx, const int* __restrict__ row_s,
                          const int* __restrict__ cnt, const float* __restrict__ w,
                          float* __restrict__ dinv, int n) {
    int i = blockIdx.x * blockDim.x + threadIdx.x;
    if (i >= n) return;
    int s0 = row_s[i], c = cnt[i];
    float d = 1.0f;
    for (int j = 0; j < c; ++j) d += w[eidx[s0 + j]];
    dinv[i] = rsqrtf(d);
}

// h1[N][64] = x[N][128] @ W1[128][64]. Wave: 32 rows, lane = output column.
__global__ void __launch_bounds__(256) k_gemm1(const float* __restrict__ x,
                                               const float* __restrict__ W1,
                                               float* __restrict__ h1, int n) {
    int lane = threadIdx.x & 63;
    int wave = __builtin_amdgcn_readfirstlane(threadIdx.x >> 6);
    int r0 = (blockIdx.x * 4 + wave) * 32;
    if (r0 >= n) return;

    float acc[32];
#pragma unroll
    for (int r = 0; r < 32; ++r) acc[r] = 0.f;

#pragma unroll 1
    for (int kc = 0; kc < 4; ++kc) {
        float wreg[32];
#pragma unroll
        for (int kk = 0; kk < 32; ++kk)
            wreg[kk] = W1[(kc * 32 + kk) * 64 + lane];
#pragma unroll
        for (int r = 0; r < 32; ++r) {
            const float4* xr = reinterpret_cast<const float4*>(
                x + (size_t)(r0 + r) * 128 + kc * 32);
#pragma unroll
            for (int q = 0; q < 8; ++q) {
                float4 xv = xr[q];
                acc[r] = fmaf(xv.x, wreg[q * 4 + 0], acc[r]);
                acc[r] = fmaf(xv.y, wreg[q * 4 + 1], acc[r]);
                acc[r] = fmaf(xv.z, wreg[q * 4 + 2], acc[r]);
                acc[r] = fmaf(xv.w, wreg[q * 4 + 3], acc[r]);
            }
        }
    }
#pragma unroll
    for (int r = 0; r < 32; ++r)
        h1[(size_t)(r0 + r) * 64 + lane] = acc[r];
}

// Layer-1 aggregate: wave per node, lane = dim (64). Fused self-loop+bias+leakyrelu.
__global__ void __launch_bounds__(256) k_gather1(
    const int* __restrict__ eidx, const int* __restrict__ row_s, const int* __restrict__ cnt,
    const int* __restrict__ src, const float* __restrict__ w, const float* __restrict__ dinv,
    const float* __restrict__ h1, const float* __restrict__ b1, float* __restrict__ y, int n) {
    int lane = threadIdx.x & 63;
    int node = blockIdx.x * 4 + (threadIdx.x >> 6);
    if (node >= n) return;
    int s0 = row_s[node], c = cnt[node];
    float di = dinv[node];
    float acc = 0.f;
    for (int j = 0; j < c; ++j) {
        int eid = eidx[s0 + j];
        int sv = src[eid];
        float nrm = dinv[sv] * w[eid] * di;
        acc = fmaf(nrm, h1[(size_t)sv * 64 + lane], acc);
    }
    float v = acc + di * di * h1[(size_t)node * 64 + lane] + b1[lane];
    y[(size_t)node * 64 + lane] = v > 0.f ? v : 0.01f * v;
}

// h2[N][4] = y[N][64] @ W2[64][4]. Thread per row; W2 in LDS.
__global__ void __launch_bounds__(256) k_gemm2(const float* __restrict__ y,
                                               const float* __restrict__ W2,
                                               float* __restrict__ h2, int n) {
    __shared__ float4 w2s[64];
    if (threadIdx.x < 64)
        w2s[threadIdx.x] = reinterpret_cast<const float4*>(W2)[threadIdx.x];
    __syncthreads();
    int i = blockIdx.x * blockDim.x + threadIdx.x;
    if (i >= n) return;
    const float4* yr = reinterpret_cast<const float4*>(y + (size_t)i * 64);
    float ax = 0.f, ay = 0.f, az = 0.f, aw = 0.f;
#pragma unroll
    for (int q = 0; q < 16; ++q) {
        float4 yv = yr[q];
#pragma unroll
        for (int j = 0; j < 4; ++j) {
            float yk = (j == 0) ? yv.x : (j == 1) ? yv.y : (j == 2) ? yv.z : yv.w;
            float4 wv = w2s[q * 4 + j];
            ax = fmaf(yk, wv.x, ax);
            ay = fmaf(yk, wv.y, ay);
            az = fmaf(yk, wv.z, az);
            aw = fmaf(yk, wv.w, aw);
        }
    }
    float4 acc = {ax, ay, az, aw};
    reinterpret_cast<float4*>(h2)[i] = acc;
}

// Layer-2 aggregate: 4 lanes per node (lane&3 = dim). Fused self+bias+softmax
// via quad shuffles.
__global__ void __launch_bounds__(256) k_gather2(
    const int* __restrict__ eidx, const int* __restrict__ row_s, const int* __restrict__ cnt,
    const int* __restrict__ src, const float* __restrict__ w, const float* __restrict__ dinv,
    const float* __restrict__ h2, const float* __restrict__ b2, float* __restrict__ out, int n) {
    int t = blockIdx.x * blockDim.x + threadIdx.x;
    int node = t >> 2, dim = t & 3;
    if (node >= n) return;
    int s0 = row_s[node], c = cnt[node];
    float di = dinv[node];
    float acc = 0.f;
    for (int j = 0; j < c; ++j) {
        int eid = eidx[s0 + j];
        int sv = src[eid];
        float nrm = dinv[sv] * w[eid] * di;
        acc = fmaf(nrm, h2[(size_t)sv * 4 + dim], acc);
    }
    float v = acc + di * di * h2[(size_t)node * 4 + dim] + b2[dim];
    float m = v;
    m = fmaxf(m, __shfl_xor(m, 1));
    m = fmaxf(m, __shfl_xor(m, 2));
    float ex = expf(v - m);
    float s = ex;
    s += __shfl_xor(s, 1);
    s += __shfl_xor(s, 2);
    out[(size_t)node * 4 + dim] = ex / s;
}

extern "C" void kernel_launch(void* const* d_in, const int* in_sizes, int n_in,
                              void* d_out, int out_size, void* d_ws, size_t ws_size,
                              hipStream_t stream) {
    const float* x  = (const float*)d_in[0];
    const int*   ei = (const int*)d_in[1];
    const float* w  = (const float*)d_in[2];
    const float* W1 = (const float*)d_in[3];
    const float* b1 = (const float*)d_in[4];
    const float* W2 = (const float*)d_in[5];
    const float* b2 = (const float*)d_in[6];
    int n = in_sizes[0] / 128;
    int E = in_sizes[2];
    const int* src = ei;
    const int* dst = ei + E;

    // workspace layout (~67.2 MB)
    char* p = (char*)d_ws;
    int* cnt    = (int*)p;              p += (size_t)n * 4;
    int* row_s  = (int*)p;              p += (size_t)n * 4;
    int* cursor = (int*)p;              p += (size_t)n * 4;
    int* bsum   = (int*)p;              p += 512 * 4;
    int* eidx   = (int*)p;              p += (size_t)E * 4;
    float* dinv = (float*)p;            p += (size_t)n * 4;
    float* h1   = (float*)p;            p += (size_t)n * 64 * 4;
    float* y    = (float*)p;            p += (size_t)n * 64 * 4;
    float* h2   = (float*)p;            p += (size_t)n * 4 * 4;

    hipMemsetAsync(cnt, 0, (size_t)n * 4, stream);
    hipMemsetAsync(cursor, 0, (size_t)n * 4, stream);

    int nb = (n + SCAN_BLK - 1) / SCAN_BLK;  // 391 <= 512

    k_hist<<<(E + 255) / 256, 256, 0, stream>>>(dst, cnt, E);
    k_scan1<<<nb, SCAN_BLK, 0, stream>>>(cnt, row_s, bsum, n);
    k_scan2<<<1, 512, 0, stream>>>(bsum, nb);
    k_scan3<<<nb, SCAN_BLK, 0, stream>>>(row_s, bsum, n);
    k_fill<<<(E + 255) / 256, 256, 0, stream>>>(dst, row_s, cursor, eidx, E);
    k_deg_csr<<<(n + 255) / 256, 256, 0, stream>>>(eidx, row_s, cnt, w, dinv, n);

    k_gemm1<<<(n + 127) / 128, 256, 0, stream>>>(x, W1, h1, n);
    k_gather1<<<(n + 3) / 4, 256, 0, stream>>>(eidx, row_s, cnt, src, w, dinv, h1, b1, y, n);
    k_gemm2<<<(n + 255) / 256, 256, 0, stream>>>(y, W2, h2, n);
    k_gather2<<<((size_t)n * 4 + 255) / 256, 256, 0, stream>>>(eidx, row_s, cnt, src, w, dinv,
                                                               h2, b2, (float*)d_out, n);
}

// Round 8
// 843.015 us; speedup vs baseline: 4.3403x; 1.5206x over previous
//
#include <hip/hip_runtime.h>

// GCN 2-layer, CSR gather, packed (src,norm) slots, fused gemm2.
// Pipeline: memset -> hist+deg -> dinv -> scan(3) -> fill(pack) -> gemm1 ->
//           agg1(+leakyrelu+gemm2) -> agg2(+softmax)

#define SCAN_BLK 256

// cnt[dst]++ (int) and deg[dst] += w (float), one pass over edges.
__global__ void k_hist_deg(const int* __restrict__ dst, const float* __restrict__ w,
                           int* __restrict__ cnt, float* __restrict__ deg, int E) {
    int e = blockIdx.x * blockDim.x + threadIdx.x;
    if (e < E) {
        int d = dst[e];
        atomicAdd(&cnt[d], 1);
        unsafeAtomicAdd(&deg[d], w[e]);
    }
}

// dinv = rsqrt(deg + 1)  (self-loop weight 1), in place over deg.
__global__ void k_dinv(float* __restrict__ deg, int n) {
    int i = blockIdx.x * blockDim.x + threadIdx.x;
    if (i < n) deg[i] = rsqrtf(deg[i] + 1.0f);
}

// exclusive scan, 3-kernel
__global__ void k_scan1(const int* __restrict__ cnt, int* __restrict__ pre,
                        int* __restrict__ bsum, int n) {
    __shared__ int s[SCAN_BLK];
    int i = blockIdx.x * SCAN_BLK + threadIdx.x;
    int v = (i < n) ? cnt[i] : 0;
    s[threadIdx.x] = v;
    __syncthreads();
#pragma unroll
    for (int off = 1; off < SCAN_BLK; off <<= 1) {
        int t = (threadIdx.x >= off) ? s[threadIdx.x - off] : 0;
        __syncthreads();
        s[threadIdx.x] += t;
        __syncthreads();
    }
    if (i < n) pre[i] = s[threadIdx.x] - v;
    if (threadIdx.x == SCAN_BLK - 1) bsum[blockIdx.x] = s[threadIdx.x];
}

__global__ void k_scan2(int* __restrict__ bsum, int nb) {  // nb <= 512
    __shared__ int s[512];
    int v = (threadIdx.x < nb) ? bsum[threadIdx.x] : 0;
    s[threadIdx.x] = v;
    __syncthreads();
#pragma unroll
    for (int off = 1; off < 512; off <<= 1) {
        int t = (threadIdx.x >= off) ? s[threadIdx.x - off] : 0;
        __syncthreads();
        s[threadIdx.x] += t;
        __syncthreads();
    }
    if (threadIdx.x < nb) bsum[threadIdx.x] = s[threadIdx.x] - v;
}

__global__ void k_scan3(int* __restrict__ pre, const int* __restrict__ bsum, int n) {
    int i = blockIdx.x * SCAN_BLK + threadIdx.x;
    if (i < n) pre[i] += bsum[blockIdx.x];
}

// pack[slot] = {src, norm} with norm = dinv[src]*w*dinv[dst] (dinv already known).
__global__ void k_fill(const int* __restrict__ src, const int* __restrict__ dst,
                       const float* __restrict__ w, const float* __restrict__ dinv,
                       const int* __restrict__ row_s, int* __restrict__ cursor,
                       int2* __restrict__ pack, int E) {
    int e = blockIdx.x * blockDim.x + threadIdx.x;
    if (e >= E) return;
    int d = dst[e], s = src[e];
    float nm = dinv[s] * w[e] * dinv[d];
    int p = atomicAdd(&cursor[d], 1);
    int2 pk;
    pk.x = s;
    pk.y = __float_as_int(nm);
    pack[row_s[d] + p] = pk;
}

// h1[N][64] = x[N][128] @ W1[128][64]. Wave: 32 rows, lane = output column.
__global__ void __launch_bounds__(256) k_gemm1(const float* __restrict__ x,
                                               const float* __restrict__ W1,
                                               float* __restrict__ h1, int n) {
    int lane = threadIdx.x & 63;
    int wave = __builtin_amdgcn_readfirstlane(threadIdx.x >> 6);
    int r0 = (blockIdx.x * 4 + wave) * 32;
    if (r0 >= n) return;

    float acc[32];
#pragma unroll
    for (int r = 0; r < 32; ++r) acc[r] = 0.f;

#pragma unroll 1
    for (int kc = 0; kc < 4; ++kc) {
        float wreg[32];
#pragma unroll
        for (int kk = 0; kk < 32; ++kk)
            wreg[kk] = W1[(kc * 32 + kk) * 64 + lane];
#pragma unroll
        for (int r = 0; r < 32; ++r) {
            const float4* xr = reinterpret_cast<const float4*>(
                x + (size_t)(r0 + r) * 128 + kc * 32);
#pragma unroll
            for (int q = 0; q < 8; ++q) {
                float4 xv = xr[q];
                acc[r] = fmaf(xv.x, wreg[q * 4 + 0], acc[r]);
                acc[r] = fmaf(xv.y, wreg[q * 4 + 1], acc[r]);
                acc[r] = fmaf(xv.z, wreg[q * 4 + 2], acc[r]);
                acc[r] = fmaf(xv.w, wreg[q * 4 + 3], acc[r]);
            }
        }
    }
#pragma unroll
    for (int r = 0; r < 32; ++r)
        h1[(size_t)(r0 + r) * 64 + lane] = acc[r];
}

// Layer-1 aggregate fused with leaky-relu and gemm2 (64->4).
// Wave per node, lane = dim. Edge (src,norm) pairs loaded 64-at-a-time
// coalesced, broadcast via shfl; 4 h1-row loads in flight.
__global__ void __launch_bounds__(256) k_agg1(
    const int2* __restrict__ pack, const int* __restrict__ row_s, const int* __restrict__ cnt,
    const float* __restrict__ dinv, const float* __restrict__ h1, const float* __restrict__ b1,
    const float* __restrict__ W2, float* __restrict__ h2, int n) {
    int lane = threadIdx.x & 63;
    int node = blockIdx.x * 4 + (threadIdx.x >> 6);
    if (node >= n) return;
    int s0 = row_s[node], c = cnt[node];
    float di = dinv[node];
    float selfh = h1[(size_t)node * 64 + lane];  // issue early
    const int2* pp = pack + s0;

    float a0 = 0.f, a1 = 0.f, a2 = 0.f, a3 = 0.f;
    for (int base = 0; base < c; base += 64) {
        int take = min(c - base, 64);
        int2 pk = (lane < take) ? pp[base + lane] : make_int2(0, 0);
        int svl = pk.x;
        float nml = __int_as_float(pk.y);
        int j = 0;
        for (; j + 4 <= take; j += 4) {
            int sv0 = __shfl(svl, j), sv1 = __shfl(svl, j + 1);
            int sv2 = __shfl(svl, j + 2), sv3 = __shfl(svl, j + 3);
            float n0 = __shfl(nml, j), n1 = __shfl(nml, j + 1);
            float n2 = __shfl(nml, j + 2), n3 = __shfl(nml, j + 3);
            float r0 = h1[(size_t)sv0 * 64 + lane];
            float r1 = h1[(size_t)sv1 * 64 + lane];
            float r2 = h1[(size_t)sv2 * 64 + lane];
            float r3 = h1[(size_t)sv3 * 64 + lane];
            a0 = fmaf(n0, r0, a0);
            a1 = fmaf(n1, r1, a1);
            a2 = fmaf(n2, r2, a2);
            a3 = fmaf(n3, r3, a3);
        }
        for (; j < take; ++j) {
            int sv = __shfl(svl, j);
            float nm = __shfl(nml, j);
            a0 = fmaf(nm, h1[(size_t)sv * 64 + lane], a0);
        }
    }
    float v = (a0 + a1) + (a2 + a3) + di * di * selfh + b1[lane];
    v = v > 0.f ? v : 0.01f * v;  // leaky_relu -> y[node][lane]

    // gemm2 row: h2[node][d] = sum_lane v * W2[lane][d]
    float4 wv = reinterpret_cast<const float4*>(W2)[lane];
    float px = v * wv.x, py = v * wv.y, pz = v * wv.z, pw = v * wv.w;
#pragma unroll
    for (int off = 32; off; off >>= 1) {
        px += __shfl_xor(px, off);
        py += __shfl_xor(py, off);
        pz += __shfl_xor(pz, off);
        pw += __shfl_xor(pw, off);
    }
    if (lane == 0) {
        float4 o = {px, py, pz, pw};
        reinterpret_cast<float4*>(h2)[node] = o;
    }
}

// Layer-2 aggregate + softmax. Wave per node: 16 edge-groups x 4 dims,
// shuffle reduction over groups, quad-shuffle softmax.
__global__ void __launch_bounds__(256) k_agg2(
    const int2* __restrict__ pack, const int* __restrict__ row_s, const int* __restrict__ cnt,
    const float* __restrict__ dinv, const float* __restrict__ h2, const float* __restrict__ b2,
    float* __restrict__ out, int n) {
    int lane = threadIdx.x & 63;
    int node = blockIdx.x * 4 + (threadIdx.x >> 6);
    if (node >= n) return;
    int dim = lane & 3, grp = lane >> 2;
    int s0 = row_s[node], c = cnt[node];
    float di = dinv[node];
    float acc = 0.f;
    for (int j = grp; j < c; j += 16) {
        int2 pk = pack[s0 + j];
        float nm = __int_as_float(pk.y);
        acc = fmaf(nm, h2[(size_t)pk.x * 4 + dim], acc);
    }
    acc += __shfl_xor(acc, 4);
    acc += __shfl_xor(acc, 8);
    acc += __shfl_xor(acc, 16);
    acc += __shfl_xor(acc, 32);
    float v = acc + di * di * h2[(size_t)node * 4 + dim] + b2[dim];
    float m = v;
    m = fmaxf(m, __shfl_xor(m, 1));
    m = fmaxf(m, __shfl_xor(m, 2));
    float ex = expf(v - m);
    float s = ex;
    s += __shfl_xor(s, 1);
    s += __shfl_xor(s, 2);
    if (lane < 4) out[(size_t)node * 4 + lane] = ex / s;
}

extern "C" void kernel_launch(void* const* d_in, const int* in_sizes, int n_in,
                              void* d_out, int out_size, void* d_ws, size_t ws_size,
                              hipStream_t stream) {
    const float* x  = (const float*)d_in[0];
    const int*   ei = (const int*)d_in[1];
    const float* w  = (const float*)d_in[2];
    const float* W1 = (const float*)d_in[3];
    const float* b1 = (const float*)d_in[4];
    const float* W2 = (const float*)d_in[5];
    const float* b2 = (const float*)d_in[6];
    int n = in_sizes[0] / 128;
    int E = in_sizes[2];
    const int* src = ei;
    const int* dst = ei + E;

    // workspace (~54.4 MB): [cnt n][cursor n][deg n][row_s n][bsum 512][pack E*2][h1 n*64][h2 n*4]
    char* p = (char*)d_ws;
    int*   cnt    = (int*)p;    p += (size_t)n * 4;
    int*   cursor = (int*)p;    p += (size_t)n * 4;
    float* deg    = (float*)p;  p += (size_t)n * 4;   // becomes dinv in place
    int*   row_s  = (int*)p;    p += (size_t)n * 4;
    int*   bsum   = (int*)p;    p += 512 * 4;
    int2*  pack   = (int2*)p;   p += (size_t)E * 8;
    float* h1     = (float*)p;  p += (size_t)n * 64 * 4;
    float* h2     = (float*)p;  p += (size_t)n * 4 * 4;
    float* dinv   = deg;

    hipMemsetAsync(cnt, 0, (size_t)n * 3 * 4, stream);  // cnt, cursor, deg

    int nb = (n + SCAN_BLK - 1) / SCAN_BLK;  // 391 <= 512

    k_hist_deg<<<(E + 255) / 256, 256, 0, stream>>>(dst, w, cnt, deg, E);
    k_dinv<<<(n + 255) / 256, 256, 0, stream>>>(deg, n);
    k_scan1<<<nb, SCAN_BLK, 0, stream>>>(cnt, row_s, bsum, n);
    k_scan2<<<1, 512, 0, stream>>>(bsum, nb);
    k_scan3<<<nb, SCAN_BLK, 0, stream>>>(row_s, bsum, n);
    k_fill<<<(E + 255) / 256, 256, 0, stream>>>(src, dst, w, dinv, row_s, cursor, pack, E);

    k_gemm1<<<(n + 127) / 128, 256, 0, stream>>>(x, W1, h1, n);
    k_agg1<<<(n + 3) / 4, 256, 0, stream>>>(pack, row_s, cnt, dinv, h1, b1, W2, h2, n);
    k_agg2<<<(n + 3) / 4, 256, 0, stream>>>(pack, row_s, cnt, dinv, h2, b2, (float*)d_out, n);
}

// Round 11
// 654.525 us; speedup vs baseline: 5.5902x; 1.2880x over previous
//
#include <hip/hip_runtime.h>

// GCN 2-layer, CSR gather. Single atomic pass (hist returns slot idx);
// deg/norm via CSR sweeps; agg1 fuses leakyrelu+gemm2; agg2 fuses softmax.
// Pipeline: memset(cnt) -> hist(sidx) -> scan(3) -> fill -> degdinv ->
//           normpack -> gemm1 -> agg1 -> agg2

#define SCAN_BLK 256

// sidx[e] = arrival order of edge e within its dst bucket.
__global__ void k_hist(const int* __restrict__ dst, int* __restrict__ cnt,
                       int* __restrict__ sidx, int E) {
    int e = blockIdx.x * blockDim.x + threadIdx.x;
    if (e < E) sidx[e] = atomicAdd(&cnt[dst[e]], 1);
}

// exclusive scan, 3-kernel
__global__ void k_scan1(const int* __restrict__ cnt, int* __restrict__ pre,
                        int* __restrict__ bsum, int n) {
    __shared__ int s[SCAN_BLK];
    int i = blockIdx.x * SCAN_BLK + threadIdx.x;
    int v = (i < n) ? cnt[i] : 0;
    s[threadIdx.x] = v;
    __syncthreads();
#pragma unroll
    for (int off = 1; off < SCAN_BLK; off <<= 1) {
        int t = (threadIdx.x >= off) ? s[threadIdx.x - off] : 0;
        __syncthreads();
        s[threadIdx.x] += t;
        __syncthreads();
    }
    if (i < n) pre[i] = s[threadIdx.x] - v;
    if (threadIdx.x == SCAN_BLK - 1) bsum[blockIdx.x] = s[threadIdx.x];
}

__global__ void k_scan2(int* __restrict__ bsum, int nb) {  // nb <= 512
    __shared__ int s[512];
    int v = (threadIdx.x < nb) ? bsum[threadIdx.x] : 0;
    s[threadIdx.x] = v;
    __syncthreads();
#pragma unroll
    for (int off = 1; off < 512; off <<= 1) {
        int t = (threadIdx.x >= off) ? s[threadIdx.x - off] : 0;
        __syncthreads();
        s[threadIdx.x] += t;
        __syncthreads();
    }
    if (threadIdx.x < nb) bsum[threadIdx.x] = s[threadIdx.x] - v;
}

__global__ void k_scan3(int* __restrict__ pre, const int* __restrict__ bsum, int n) {
    int i = blockIdx.x * SCAN_BLK + threadIdx.x;
    if (i < n) pre[i] += bsum[blockIdx.x];
}

// pack[slot] = {src, w}; slot = row_s[dst] + sidx. No atomics.
__global__ void k_fill(const int* __restrict__ src, const int* __restrict__ dst,
                       const float* __restrict__ w, const int* __restrict__ row_s,
                       const int* __restrict__ sidx, int2* __restrict__ pack, int E) {
    int e = blockIdx.x * blockDim.x + threadIdx.x;
    if (e >= E) return;
    int2 pk;
    pk.x = src[e];
    pk.y = __float_as_int(w[e]);
    pack[row_s[dst[e]] + sidx[e]] = pk;
}

// dinv[node] = rsqrt(1 + sum_row w). Wave per node, lane-strided row sweep.
__global__ void __launch_bounds__(256) k_degdinv(const int2* __restrict__ pack,
                                                 const int* __restrict__ row_s,
                                                 const int* __restrict__ cnt,
                                                 float* __restrict__ dinv, int n) {
    int lane = threadIdx.x & 63;
    int node = blockIdx.x * 4 + (threadIdx.x >> 6);
    if (node >= n) return;
    int s0 = row_s[node], c = cnt[node];
    float acc = 0.f;
    for (int j = lane; j < c; j += 64) acc += __int_as_float(pack[s0 + j].y);
#pragma unroll
    for (int off = 32; off; off >>= 1) acc += __shfl_xor(acc, off);
    if (lane == 0) dinv[node] = rsqrtf(acc + 1.0f);
}

// pack.y: w -> norm = dinv[src]*w*dinv[dst]. Wave per node.
__global__ void __launch_bounds__(256) k_normpack(int2* __restrict__ pack,
                                                  const int* __restrict__ row_s,
                                                  const int* __restrict__ cnt,
                                                  const float* __restrict__ dinv, int n) {
    int lane = threadIdx.x & 63;
    int node = blockIdx.x * 4 + (threadIdx.x >> 6);
    if (node >= n) return;
    int s0 = row_s[node], c = cnt[node];
    float di = dinv[node];
    for (int j = lane; j < c; j += 64) {
        int2 pk = pack[s0 + j];
        pack[s0 + j].y = __float_as_int(__int_as_float(pk.y) * dinv[pk.x] * di);
    }
}

// h1[N][64] = x[N][128] @ W1[128][64]. Wave: 32 rows, lane = output column.
__global__ void __launch_bounds__(256) k_gemm1(const float* __restrict__ x,
                                               const float* __restrict__ W1,
                                               float* __restrict__ h1, int n) {
    int lane = threadIdx.x & 63;
    int wave = __builtin_amdgcn_readfirstlane(threadIdx.x >> 6);
    int r0 = (blockIdx.x * 4 + wave) * 32;
    if (r0 >= n) return;

    float acc[32];
#pragma unroll
    for (int r = 0; r < 32; ++r) acc[r] = 0.f;

#pragma unroll 1
    for (int kc = 0; kc < 4; ++kc) {
        float wreg[32];
#pragma unroll
        for (int kk = 0; kk < 32; ++kk)
            wreg[kk] = W1[(kc * 32 + kk) * 64 + lane];
#pragma unroll
        for (int r = 0; r < 32; ++r) {
            const float4* xr = reinterpret_cast<const float4*>(
                x + (size_t)(r0 + r) * 128 + kc * 32);
#pragma unroll
            for (int q = 0; q < 8; ++q) {
                float4 xv = xr[q];
                acc[r] = fmaf(xv.x, wreg[q * 4 + 0], acc[r]);
                acc[r] = fmaf(xv.y, wreg[q * 4 + 1], acc[r]);
                acc[r] = fmaf(xv.z, wreg[q * 4 + 2], acc[r]);
                acc[r] = fmaf(xv.w, wreg[q * 4 + 3], acc[r]);
            }
        }
    }
#pragma unroll
    for (int r = 0; r < 32; ++r)
        h1[(size_t)(r0 + r) * 64 + lane] = acc[r];
}

// Layer-1 aggregate fused with leaky-relu and gemm2 (64->4).
__global__ void __launch_bounds__(256) k_agg1(
    const int2* __restrict__ pack, const int* __restrict__ row_s, const int* __restrict__ cnt,
    const float* __restrict__ dinv, const float* __restrict__ h1, const float* __restrict__ b1,
    const float* __restrict__ W2, float* __restrict__ h2, int n) {
    int lane = threadIdx.x & 63;
    int node = blockIdx.x * 4 + (threadIdx.x >> 6);
    if (node >= n) return;
    int s0 = row_s[node], c = cnt[node];
    float di = dinv[node];
    float selfh = h1[(size_t)node * 64 + lane];  // issue early
    const int2* pp = pack + s0;

    float a0 = 0.f, a1 = 0.f, a2 = 0.f, a3 = 0.f;
    for (int base = 0; base < c; base += 64) {
        int take = min(c - base, 64);
        int2 pk = (lane < take) ? pp[base + lane] : make_int2(0, 0);
        int svl = pk.x;
        float nml = __int_as_float(pk.y);
        int j = 0;
        for (; j + 4 <= take; j += 4) {
            int sv0 = __shfl(svl, j), sv1 = __shfl(svl, j + 1);
            int sv2 = __shfl(svl, j + 2), sv3 = __shfl(svl, j + 3);
            float n0 = __shfl(nml, j), n1 = __shfl(nml, j + 1);
            float n2 = __shfl(nml, j + 2), n3 = __shfl(nml, j + 3);
            float r0 = h1[(size_t)sv0 * 64 + lane];
            float r1 = h1[(size_t)sv1 * 64 + lane];
            float r2 = h1[(size_t)sv2 * 64 + lane];
            float r3 = h1[(size_t)sv3 * 64 + lane];
            a0 = fmaf(n0, r0, a0);
            a1 = fmaf(n1, r1, a1);
            a2 = fmaf(n2, r2, a2);
            a3 = fmaf(n3, r3, a3);
        }
        for (; j < take; ++j) {
            int sv = __shfl(svl, j);
            float nm = __shfl(nml, j);
            a0 = fmaf(nm, h1[(size_t)sv * 64 + lane], a0);
        }
    }
    float v = (a0 + a1) + (a2 + a3) + di * di * selfh + b1[lane];
    v = v > 0.f ? v : 0.01f * v;  // leaky_relu -> y[node][lane]

    // gemm2 row: h2[node][d] = sum_lane v * W2[lane][d]
    float4 wv = reinterpret_cast<const float4*>(W2)[lane];
    float px = v * wv.x, py = v * wv.y, pz = v * wv.z, pw = v * wv.w;
#pragma unroll
    for (int off = 32; off; off >>= 1) {
        px += __shfl_xor(px, off);
        py += __shfl_xor(py, off);
        pz += __shfl_xor(pz, off);
        pw += __shfl_xor(pw, off);
    }
    if (lane == 0) {
        float4 o = {px, py, pz, pw};
        reinterpret_cast<float4*>(h2)[node] = o;
    }
}

// Layer-2 aggregate + softmax. Wave per node: 16 edge-groups x 4 dims.
__global__ void __launch_bounds__(256) k_agg2(
    const int2* __restrict__ pack, const int* __restrict__ row_s, const int* __restrict__ cnt,
    const float* __restrict__ dinv, const float* __restrict__ h2, const float* __restrict__ b2,
    float* __restrict__ out, int n) {
    int lane = threadIdx.x & 63;
    int node = blockIdx.x * 4 + (threadIdx.x >> 6);
    if (node >= n) return;
    int dim = lane & 3, grp = lane >> 2;
    int s0 = row_s[node], c = cnt[node];
    float di = dinv[node];
    float acc = 0.f;
    for (int j = grp; j < c; j += 16) {
        int2 pk = pack[s0 + j];
        float nm = __int_as_float(pk.y);
        acc = fmaf(nm, h2[(size_t)pk.x * 4 + dim], acc);
    }
    acc += __shfl_xor(acc, 4);
    acc += __shfl_xor(acc, 8);
    acc += __shfl_xor(acc, 16);
    acc += __shfl_xor(acc, 32);
    float v = acc + di * di * h2[(size_t)node * 4 + dim] + b2[dim];
    float m = v;
    m = fmaxf(m, __shfl_xor(m, 1));
    m = fmaxf(m, __shfl_xor(m, 2));
    float ex = expf(v - m);
    float s = ex;
    s += __shfl_xor(s, 1);
    s += __shfl_xor(s, 2);
    if (lane < 4) out[(size_t)node * 4 + lane] = ex / s;
}

extern "C" void kernel_launch(void* const* d_in, const int* in_sizes, int n_in,
                              void* d_out, int out_size, void* d_ws, size_t ws_size,
                              hipStream_t stream) {
    const float* x  = (const float*)d_in[0];
    const int*   ei = (const int*)d_in[1];
    const float* w  = (const float*)d_in[2];
    const float* W1 = (const float*)d_in[3];
    const float* b1 = (const float*)d_in[4];
    const float* W2 = (const float*)d_in[5];
    const float* b2 = (const float*)d_in[6];
    int n = in_sizes[0] / 128;
    int E = in_sizes[2];
    const int* src = ei;
    const int* dst = ei + E;

    // workspace (~66.8 MB):
    // [cnt n][row_s n][dinv n][bsum 512][sidx E][pack E*2][h1 n*64][h2 n*4]
    char* p = (char*)d_ws;
    int*   cnt   = (int*)p;    p += (size_t)n * 4;
    int*   row_s = (int*)p;    p += (size_t)n * 4;
    float* dinv  = (float*)p;  p += (size_t)n * 4;
    int*   bsum  = (int*)p;    p += 512 * 4;
    int*   sidx  = (int*)p;    p += (size_t)E * 4;
    int2*  pack  = (int2*)p;   p += (size_t)E * 8;
    float* h1    = (float*)p;  p += (size_t)n * 64 * 4;
    float* h2    = (float*)p;  p += (size_t)n * 4 * 4;

    hipMemsetAsync(cnt, 0, (size_t)n * 4, stream);

    int nb = (n + SCAN_BLK - 1) / SCAN_BLK;  // 391 <= 512

    k_hist<<<(E + 255) / 256, 256, 0, stream>>>(dst, cnt, sidx, E);
    k_scan1<<<nb, SCAN_BLK, 0, stream>>>(cnt, row_s, bsum, n);
    k_scan2<<<1, 512, 0, stream>>>(bsum, nb);
    k_scan3<<<nb, SCAN_BLK, 0, stream>>>(row_s, bsum, n);
    k_fill<<<(E + 255) / 256, 256, 0, stream>>>(src, dst, w, row_s, sidx, pack, E);
    k_degdinv<<<(n + 3) / 4, 256, 0, stream>>>(pack, row_s, cnt, dinv, n);
    k_normpack<<<(n + 3) / 4, 256, 0, stream>>>(pack, row_s, cnt, dinv, n);

    k_gemm1<<<(n + 127) / 128, 256, 0, stream>>>(x, W1, h1, n);
    k_agg1<<<(n + 3) / 4, 256, 0, stream>>>(pack, row_s, cnt, dinv, h1, b1, W2, h2, n);
    k_agg2<<<(n + 3) / 4, 256, 0, stream>>>(pack, row_s, cnt, dinv, h2, b2, (float*)d_out, n);
}